// Round 8
// baseline (72.767 us; speedup 1.0000x reference)
//
#include <hip/hip_runtime.h>

#define NN 256
#define EHID 14

typedef short short8 __attribute__((ext_vector_type(8)));
typedef float f32x16 __attribute__((ext_vector_type(16)));

__device__ __forceinline__ float sigm(float x) {
    return __builtin_amdgcn_rcpf(1.0f + __expf(-x));
}
__device__ __forceinline__ unsigned int bfbits(float f) {
    unsigned int u = __builtin_bit_cast(unsigned int, f);
    return (u + 0x7FFFu + ((u >> 16) & 1u)) >> 16;
}
__device__ __forceinline__ unsigned int cvtpk(float lo, float hi) {
    unsigned int r;
    asm("v_cvt_pk_bf16_f32 %0, %1, %2" : "=v"(r) : "v"(lo), "v"(hi));
    return r;
}
__device__ __forceinline__ short8 mk8(unsigned a, unsigned b, unsigned c, unsigned d) {
    int4 t = make_int4((int)a, (int)b, (int)c, (int)d);
    return __builtin_bit_cast(short8, t);
}

// CH independent i-chains (same batch b) sharing xj loads + mask row.
// Writes per-chain node-MLP-projected message pn (already butterfly-reduced).
template<int CH>
__device__ __forceinline__ void edge_phase(
    const float* __restrict__ xb, const int* __restrict__ mrow,
    float xa0, float xa1, float xa2,
    float xbb0, float xbb1, float xbb2,
    short8 A1, short8 A20, short8 A21,
    const float (&wgv0)[16], const float (&wgv1)[16], float bg0,
    int l31, int half,
    float (&pnA)[6], float (&pnB)[6],
    const float* __restrict__ Wn1)
{
    const float xi0[2] = {xa0, xbb0};
    const float xi1[2] = {xa1, xbb1};
    const float xi2[2] = {xa2, xbb2};

    float macc0[CH][16], macc1[CH][16];
#pragma unroll
    for (int ch = 0; ch < CH; ++ch)
#pragma unroll
        for (int r = 0; r < 16; ++r) { macc0[ch][r] = 0.f; macc1[ch][r] = 0.f; }

    unsigned p0[CH];
#pragma unroll
    for (int ch = 0; ch < CH; ++ch) p0[ch] = cvtpk(xi0[ch], xi1[ch]);

    f32x16 zc;
#pragma unroll
    for (int r = 0; r < 16; ++r) zc[r] = 0.f;

#pragma unroll 1
    for (int rnd = 0; rnd < 8; ++rnd) {
        const int e = rnd * 32 + l31;
        const float xj0 = xb[e*3+0], xj1 = xb[e*3+1], xj2 = xb[e*3+2];
        const int   mj  = mrow[e];

        short8 B2[CH];
#pragma unroll
        for (int ch = 0; ch < CH; ++ch) {
            const float r0 = xi0[ch]-xj0, r1 = xi1[ch]-xj1, r2 = xi2[ch]-xj2;
            const float rd = r0*r0 + r1*r1 + r2*r2;
            const short8 B1 = mk8(p0[ch], cvtpk(xi2[ch], xj0),
                                  cvtpk(xj1, xj2), cvtpk(rd, 1.0f));
            const f32x16 c = __builtin_amdgcn_mfma_f32_32x32x16_bf16(A1, B1, zc, 0, 0, 0);
            float s[8];
#pragma unroll
            for (int r = 0; r < 8; ++r) s[r] = c[r] * sigm(c[r]);
            const unsigned q01 = cvtpk(s[0], s[1]);
            const unsigned q23 = cvtpk(s[2], s[3]);
            const unsigned q45 = cvtpk(s[4], s[5]);
            const unsigned q67 = cvtpk(s[6], s[7]);
            const unsigned sendA = half ? q01 : q45;
            const unsigned sendB = half ? q23 : q67;
            const unsigned recvA = (unsigned)__shfl_xor((int)sendA, 32, 64);
            const unsigned recvB = (unsigned)__shfl_xor((int)sendB, 32, 64);
            const unsigned w0 = half ? recvA : q01;
            const unsigned w1 = half ? recvB : q23;
            const unsigned w2 = half ? q45   : recvA;
            const unsigned w3 = half ? 0x00003F80u : recvB;  // k14=1(b2), k15=0
            B2[ch] = mk8(w0, w1, w2, w3);
        }

#pragma unroll
        for (int ch = 0; ch < CH; ++ch) {
            const f32x16 c0 = __builtin_amdgcn_mfma_f32_32x32x16_bf16(A20, B2[ch], zc, 0, 0, 0);
            const f32x16 c1 = __builtin_amdgcn_mfma_f32_32x32x16_bf16(A21, B2[ch], zc, 0, 0, 0);
            float v0[16], v1[16];
            float gpa = 0.f, gpb = 0.f, gpc = 0.f, gpd = 0.f;
#pragma unroll
            for (int r = 0; r < 16; ++r) {
                v0[r] = c0[r] * sigm(c0[r]);
                v1[r] = c1[r] * sigm(c1[r]);
                if (r < 8) { gpa += v0[r] * wgv0[r]; gpc += v1[r] * wgv1[r]; }
                else       { gpb += v0[r] * wgv0[r]; gpd += v1[r] * wgv1[r]; }
            }
            const float gp = (gpa + gpb) + (gpc + gpd);
            const float go = __shfl_xor(gp, 32, 64);
            float g = sigm(gp + go + bg0);
            g = mj ? g : 0.f;
#pragma unroll
            for (int r = 0; r < 16; ++r) {
                macc0[ch][r] += v0[r] * g;
                macc1[ch][r] += v1[r] * g;
            }
            if (CH == 2 && ch == 0) __builtin_amdgcn_sched_barrier(0); // cap reg pressure
        }
    }

    // project through Wn1 (commutes with edge-sum), then butterfly-reduce
    float pn[CH][6];
#pragma unroll
    for (int ch = 0; ch < CH; ++ch)
#pragma unroll
        for (int u = 0; u < 6; ++u) pn[ch][u] = 0.f;
#pragma unroll
    for (int r = 0; r < 16; ++r) {
        const int row = (r & 3) + 8*(r >> 2) + 4*half;
        const float* wr0 = Wn1 + (3 + row) * 6;
        const float* wr1 = Wn1 + (3 + row + 32) * 6;
#pragma unroll
        for (int ch = 0; ch < CH; ++ch) {
            const float m0 = macc0[ch][r], m1 = macc1[ch][r];
#pragma unroll
            for (int u = 0; u < 6; ++u) pn[ch][u] += m0 * wr0[u] + m1 * wr1[u];
        }
    }
#pragma unroll
    for (int sft = 1; sft <= 32; sft <<= 1) {
#pragma unroll
        for (int ch = 0; ch < CH; ++ch)
#pragma unroll
            for (int u = 0; u < 6; ++u) pn[ch][u] += __shfl_xor(pn[ch][u], sft, 64);
    }
#pragma unroll
    for (int u = 0; u < 6; ++u) pnA[u] = pn[0][u];
    if (CH == 2) {
#pragma unroll
        for (int u = 0; u < 6; ++u) pnB[u] = pn[1][u];
    }
}

__device__ __forceinline__ void node_out(
    float* __restrict__ out, int gi, int l,
    float xi0, float xi1, float xi2, const float (&pn)[6],
    const float* __restrict__ gamma, const float* __restrict__ beta,
    const float* __restrict__ Wn1, const float* __restrict__ bn1,
    const float* __restrict__ Wn2, const float* __restrict__ bn2)
{
    const float mu  = (xi0 + xi1 + xi2) * (1.f/3.f);
    const float d0  = xi0 - mu, d1 = xi1 - mu, d2 = xi2 - mu;
    const float var = (d0*d0 + d1*d1 + d2*d2) * (1.f/3.f);
    const float rs  = rsqrtf(var + 1e-5f);
    const float n0  = d0*rs*gamma[0] + beta[0];
    const float n1  = d1*rs*gamma[1] + beta[1];
    const float n2  = d2*rs*gamma[2] + beta[2];
    float ss[6];
#pragma unroll
    for (int u = 0; u < 6; ++u) {
        const float sv = pn[u] + bn1[u] + n0*Wn1[u] + n1*Wn1[6+u] + n2*Wn1[12+u];
        ss[u] = sv * sigm(sv);
    }
    if (l < 3) {
        const float xres = (l == 0) ? xi0 : ((l == 1) ? xi1 : xi2);
        float sv = bn2[l] + xres;
#pragma unroll
        for (int u = 0; u < 6; ++u) sv += ss[u] * Wn2[u*3 + l];
        out[gi*3 + l] = sv;
    }
}

// one wave = pair (b,i) & (b,i+128); single kernel, no LDS, no barriers.
// No min-waves launch_bounds (R3: cap=64 VGPR => 590MB spill); no full
// unroll (R5: VGPR 212 => 6% occupancy).
__global__ __launch_bounds__(256) void egnn_pair(
    const float* __restrict__ x,
    const float* __restrict__ W1, const float* __restrict__ b1,
    const float* __restrict__ W2, const float* __restrict__ b2,
    const float* __restrict__ Wg, const float* __restrict__ bg,
    const float* __restrict__ gamma, const float* __restrict__ beta,
    const float* __restrict__ Wn1, const float* __restrict__ bn1,
    const float* __restrict__ Wn2, const float* __restrict__ bn2,
    const int* __restrict__ mask, float* __restrict__ out)
{
    const int tid  = threadIdx.x;
    const int wid  = tid >> 6;
    const int l    = tid & 63;
    const int l31  = l & 31;
    const int half = l >> 5;
    const int pairid = blockIdx.x * 4 + wid;      // 0..4095
    const int b  = pairid >> 7;
    const int i0 = pairid & 127;
    const int i1 = i0 + 128;

    const float* xb   = x + b * (NN * 3);
    const int*   mrow = mask + b * NN;
    const float xa0 = xb[i0*3+0], xa1 = xb[i0*3+1], xa2 = xb[i0*3+2];
    const float xc0 = xb[i1*3+0], xc1 = xb[i1*3+1], xc2 = xb[i1*3+2];
    const int mA = mrow[i0];
    const int mB = mrow[i1];

    float pnA[6], pnB[6];
#pragma unroll
    for (int u = 0; u < 6; ++u) { pnA[u] = 0.f; pnB[u] = 0.f; }

    if (mA | mB) {
        // ---- wave-invariant weight fragments ----
        unsigned a1p[4];
#pragma unroll
        for (int e2 = 0; e2 < 4; ++e2) {
            const int k0 = 8*half + 2*e2, k1 = k0 + 1;
            float w0 = 0.f, w1 = 0.f;
            if (l31 < EHID) {
                w0 = (k0 < 7) ? W1[k0*EHID + l31] : ((k0 == 7) ? b1[l31] : 0.f);
                w1 = (k1 < 7) ? W1[k1*EHID + l31] : ((k1 == 7) ? b1[l31] : 0.f);
            }
            a1p[e2] = bfbits(w0) | (bfbits(w1) << 16);
        }
        const short8 A1 = mk8(a1p[0], a1p[1], a1p[2], a1p[3]);

        unsigned a2p[2][4];
#pragma unroll
        for (int mf = 0; mf < 2; ++mf) {
            const int ch = l31 + 32*mf;
#pragma unroll
            for (int e2 = 0; e2 < 4; ++e2) {
                const int k0 = 8*half + 2*e2, k1 = k0 + 1;
                const float w0 = (k0 < EHID) ? W2[k0*64 + ch] : ((k0 == EHID) ? b2[ch] : 0.f);
                const float w1 = (k1 < EHID) ? W2[k1*64 + ch] : ((k1 == EHID) ? b2[ch] : 0.f);
                a2p[mf][e2] = bfbits(w0) | (bfbits(w1) << 16);
            }
        }
        const short8 A20 = mk8(a2p[0][0], a2p[0][1], a2p[0][2], a2p[0][3]);
        const short8 A21 = mk8(a2p[1][0], a2p[1][1], a2p[1][2], a2p[1][3]);

        float wgv0[16], wgv1[16];
#pragma unroll
        for (int r = 0; r < 16; ++r) {
            const int row = (r & 3) + 8*(r >> 2) + 4*half;
            wgv0[r] = Wg[row];
            wgv1[r] = Wg[row + 32];
        }
        const float bg0 = bg[0];

        if (mA && mB) {
            edge_phase<2>(xb, mrow, xa0, xa1, xa2, xc0, xc1, xc2,
                          A1, A20, A21, wgv0, wgv1, bg0, l31, half,
                          pnA, pnB, Wn1);
        } else if (mA) {
            edge_phase<1>(xb, mrow, xa0, xa1, xa2, xa0, xa1, xa2,
                          A1, A20, A21, wgv0, wgv1, bg0, l31, half,
                          pnA, pnB, Wn1);
        } else {
            edge_phase<1>(xb, mrow, xc0, xc1, xc2, xc0, xc1, xc2,
                          A1, A20, A21, wgv0, wgv1, bg0, l31, half,
                          pnB, pnA, Wn1);
        }
    }

    node_out(out, b*NN + i0, l, xa0, xa1, xa2, pnA,
             gamma, beta, Wn1, bn1, Wn2, bn2);
    node_out(out, b*NN + i1, l, xc0, xc1, xc2, pnB,
             gamma, beta, Wn1, bn1, Wn2, bn2);
}

extern "C" void kernel_launch(void* const* d_in, const int* in_sizes, int n_in,
                              void* d_out, int out_size, void* d_ws, size_t ws_size,
                              hipStream_t stream) {
    (void)in_sizes; (void)n_in; (void)out_size; (void)d_ws; (void)ws_size;
    const float* x     = (const float*)d_in[0];
    const float* W1    = (const float*)d_in[1];
    const float* b1    = (const float*)d_in[2];
    const float* W2    = (const float*)d_in[3];
    const float* b2    = (const float*)d_in[4];
    const float* Wg    = (const float*)d_in[5];
    const float* bg    = (const float*)d_in[6];
    const float* gamma = (const float*)d_in[7];
    const float* beta  = (const float*)d_in[8];
    const float* Wn1   = (const float*)d_in[9];
    const float* bn1   = (const float*)d_in[10];
    const float* Wn2   = (const float*)d_in[11];
    const float* bn2   = (const float*)d_in[12];
    const int*   mask  = (const int*)d_in[13];
    float* out = (float*)d_out;

    dim3 grid((32 * NN / 2) / 4);   // 4096 pairs, 4 waves/block => 1024 blocks
    dim3 block(256);
    hipLaunchKernelGGL(egnn_pair, grid, block, 0, stream,
                       x, W1, b1, W2, b2, Wg, bg, gamma, beta,
                       Wn1, bn1, Wn2, bn2, mask, out);
}